// Round 2
// baseline (407.916 us; speedup 1.0000x reference)
//
#include <hip/hip_runtime.h>
#include <math.h>

// GAT layer, round 13: ELIMINATE global_load_lds from the Adj stream.
// R12 (counted vmcnt) was neutral -> barrier-drain theory wrong (4 blocks/CU
// TLP already covered the drain). The invariant across ALL ~2.3 TB/s variants
// (R1-R12) is the LDS-DMA (global_load_lds) path itself; the proven 6.3+ TB/s
// datapoints (harness 1-GiB fills, m13 float4 copy) use plain VMEM. LDS was
// only needed to exchange mask rows across waves -- but the MFMA A-fragment
// (lane n+16q needs row n, cols q*8..+7) is a legal direct-load pattern:
// 16 rows x 128 B aligned segments per wave instr, every line fully consumed.
// So: no LDS staging, no barriers in the hot loop, Adj -> VGPR directly,
// 2048 blocks (8/CU target) for TLP. Block-level LDS reduction of the 4
// wave-partials shrinks numP 16.8 -> 8.4 MB.
// Prediction: attn ~117 -> ~55 us, total ~395 -> ~330. Neutral => attn is not
// the dominant kernel; target k_fused next.
// N=8192, IN=512, D=64, ALPHA=0.2
//
// ws layout (float-slot units):
//   s1    : [8192] f32                          8192
//   s2    : [8192] f32                          8192
//   hFrag : [256 jblk][4 dt][64 lane] bf16x8 -> 262144 float slots
//   numP  : [2048 blk][16 r][64 d] f32          2097152
//   denP  : [2048 blk][16 r] f32                  32768

#define NN 8192
#define KIN 512
#define DD 64
#define ALPHA 0.2f

using floatx4 = __attribute__((ext_vector_type(4))) float;
using bf16x8  = __attribute__((ext_vector_type(8))) __bf16;

// ------- Kernel 1: fused  h-tile GEMM -> {s1, s2, hFrag}  (h stays on-chip) -------
__global__ __launch_bounds__(256) void k_fused(const float* __restrict__ X,
                                               const float* __restrict__ W,
                                               const float* __restrict__ a,
                                               float* __restrict__ s1,
                                               float* __restrict__ s2,
                                               __bf16* __restrict__ hFrag) {
    __shared__ __align__(16) float smem[3200];  // XT[32*36]+WL[32*64] / reused as hT[32*66]
    float* XT = smem;             // [k][row], stride 36
    float* WL = smem + 32 * 36;   // [k][d]
    float* hT = smem;             // [row][d], stride 66 (reused after final sync)
    const int t = threadIdx.x;
    const int i0 = blockIdx.x * 32;
    const int rb = t >> 5;   // rows rb*4..+3
    const int db = t & 31;   // dims db*2..+1
    float acc[4][2] = {};

    for (int k0 = 0; k0 < KIN; k0 += 32) {
        {
            const int row = t >> 3, kq = t & 7;
            const float4 x4 = *(const float4*)(X + (size_t)(i0 + row) * KIN + k0 + kq * 4);
            XT[(kq * 4 + 0) * 36 + row] = x4.x;
            XT[(kq * 4 + 1) * 36 + row] = x4.y;
            XT[(kq * 4 + 2) * 36 + row] = x4.z;
            XT[(kq * 4 + 3) * 36 + row] = x4.w;
#pragma unroll
            for (int p = 0; p < 2; ++p) {
                const int q = p * 256 + t;  // 0..511
                const int kk = q >> 4, dq = q & 15;
                *(float4*)(WL + kk * 64 + dq * 4) =
                    *(const float4*)(W + (size_t)(k0 + kk) * DD + dq * 4);
            }
        }
        __syncthreads();
#pragma unroll
        for (int k = 0; k < 32; ++k) {
            const float4 xa = *(const float4*)(XT + k * 36 + rb * 4);
            const float2 wb = *(const float2*)(WL + k * 64 + db * 2);
            const float xv[4] = {xa.x, xa.y, xa.z, xa.w};
#pragma unroll
            for (int i = 0; i < 4; ++i) {
                acc[i][0] += xv[i] * wb.x;
                acc[i][1] += xv[i] * wb.y;
            }
        }
        __syncthreads();
    }
#pragma unroll
    for (int i = 0; i < 4; ++i) {
        hT[(rb * 4 + i) * 66 + db * 2 + 0] = acc[i][0];
        hT[(rb * 4 + i) * 66 + db * 2 + 1] = acc[i][1];
    }
    __syncthreads();
    {
        const int r = t >> 3, sub = t & 7;
        float p1 = 0.f, p2 = 0.f;
#pragma unroll
        for (int u = 0; u < 8; ++u) {
            const int d = sub * 8 + u;
            const float v = hT[r * 66 + d];
            p1 += v * a[d];
            p2 += v * a[64 + d];
        }
#pragma unroll
        for (int off = 1; off < 8; off <<= 1) {
            p1 += __shfl_xor(p1, off, 64);
            p2 += __shfl_xor(p2, off, 64);
        }
        if (sub == 0) {
            s1[i0 + r] = p1;
            s2[i0 + r] = p2;
        }
    }
    {
        const int lane = t & 63, dt = t >> 6;
        const int n = lane & 15, q = lane >> 4;
        bf16x8 v;
#pragma unroll
        for (int jj = 0; jj < 8; ++jj)
            v[jj] = (__bf16)hT[(q * 8 + jj) * 66 + dt * 16 + n];
        *(bf16x8*)(hFrag + ((size_t)blockIdx.x * 256 + t) * 8) = v;
    }
}

// ------- Kernel 2: direct-load Adj stream + masked softmax MFMA (no LDS staging) -------
// 2048 blocks x 256 threads (4 waves); block = 16 rows x 2048 j (j-quarter).
// Wave wv owns j-range wv*512..+511 = 16 K-steps, loading its own masks
// straight to VGPRs (2 x dwordx4 per lane per step: 16 rows x 128 B aligned
// full-line segments per wave instr). No barriers in the hot loop; latency
// hidden by unroll-2 ILP + up to 8 blocks/CU TLP. Wave partials reduced
// across the block in LDS at the end (one 16x64 tile + 16 dens per block).
__global__ __launch_bounds__(256) void k_attn_d(const bf16x8* __restrict__ hFrag,
                                                const int* __restrict__ Adj,
                                                const float* __restrict__ s1,
                                                const float* __restrict__ s2,
                                                float* __restrict__ numP,
                                                float* __restrict__ denP) {
    __shared__ float redN[4 * 16 * 66];  // [wv][r][d], stride 66 (bank-spread)
    __shared__ float redD[4 * 16];
    const int t = threadIdx.x;
    const int wv = t >> 6, lane = t & 63;
    const int n = lane & 15, q = lane >> 4;
    const int i0 = (blockIdx.x >> 2) * 16;
    const int jb0 = (blockIdx.x & 3) * 2048 + wv * 512;
    const float s1v = s1[i0 + n];
    const int* __restrict__ arow = Adj + (size_t)(i0 + n) * NN;

    bf16x8 ones;
#pragma unroll
    for (int u = 0; u < 8; ++u) ones[u] = (__bf16)1.0f;

    floatx4 acc[5] = {};  // 4 d-tiles + denominator (B = ones)

#pragma unroll 2
    for (int ks = 0; ks < 16; ++ks) {
        const int jg = jb0 + ks * 32 + q * 8;
        const int4 m0 = *(const int4*)(arow + jg);
        const int4 m1 = *(const int4*)(arow + jg + 4);
        const float4 z0 = *(const float4*)(s2 + jg);
        const float4 z1 = *(const float4*)(s2 + jg + 4);
        const int am[8] = {m0.x, m0.y, m0.z, m0.w, m1.x, m1.y, m1.z, m1.w};
        const float zz[8] = {z0.x, z0.y, z0.z, z0.w, z1.x, z1.y, z1.z, z1.w};
        bf16x8 af;
#pragma unroll
        for (int u = 0; u < 8; ++u) {
            const float s = s1v + zz[u];
            const float l = fmaxf(s, ALPHA * s);  // leaky-relu (alpha<1)
            const float e = am[u] ? __expf(l) : 0.f;
            af[u] = (__bf16)e;
        }
        const bf16x8* hf = hFrag + (size_t)(jg >> 5) * 256 + lane;
#pragma unroll
        for (int dt = 0; dt < 4; ++dt)
            acc[dt] = __builtin_amdgcn_mfma_f32_16x16x32_bf16(af, hf[dt * 64], acc[dt], 0, 0, 0);
        acc[4] = __builtin_amdgcn_mfma_f32_16x16x32_bf16(af, ones, acc[4], 0, 0, 0);
    }

    // ---- block-level reduction of the 4 wave-partials via LDS ----
    // acc tile layout: row m = q*4+reg, col d = dt*16+n
#pragma unroll
    for (int dt = 0; dt < 4; ++dt)
#pragma unroll
        for (int r = 0; r < 4; ++r)
            redN[wv * 1056 + (q * 4 + r) * 66 + dt * 16 + n] = acc[dt][r];
    if (n == 0) {
#pragma unroll
        for (int r = 0; r < 4; ++r)
            redD[wv * 16 + q * 4 + r] = acc[4][r];
    }
    __syncthreads();
#pragma unroll
    for (int k = 0; k < 4; ++k) {
        const int idx = k * 256 + t;          // 0..1023
        const int r = idx >> 6, d = idx & 63;
        float num = 0.f;
#pragma unroll
        for (int w = 0; w < 4; ++w) num += redN[w * 1056 + r * 66 + d];
        numP[(size_t)blockIdx.x * 1024 + idx] = num;
    }
    if (t < 16) {
        float den = 0.f;
#pragma unroll
        for (int w = 0; w < 4; ++w) den += redD[w * 16 + t];
        denP[(size_t)blockIdx.x * 16 + t] = den;
    }
}

// ------- Kernel 3: reduce 4 j-quarter partials + normalize -------
__global__ __launch_bounds__(256) void k_final(const float* __restrict__ numP,
                                               const float* __restrict__ denP,
                                               float* __restrict__ out) {
    const int idx = blockIdx.x * 256 + threadIdx.x;  // 0..524287
    const int i = idx >> 6, d = idx & 63;
    const int it = i >> 4, r = i & 15;
    float num = 0.f, den = 0.f;
#pragma unroll
    for (int jq = 0; jq < 4; ++jq) {
        const size_t b = (size_t)(it * 4 + jq);
        num += numP[b * 1024 + (size_t)r * 64 + d];
        den += denP[b * 16 + r];
    }
    out[idx] = num / den;
}

extern "C" void kernel_launch(void* const* d_in, const int* in_sizes, int n_in,
                              void* d_out, int out_size, void* d_ws, size_t ws_size,
                              hipStream_t stream) {
    const float* X = (const float*)d_in[0];
    const int* Adj = (const int*)d_in[1];
    const float* W = (const float*)d_in[2];
    const float* a = (const float*)d_in[3];
    float* out = (float*)d_out;

    float* ws = (float*)d_ws;
    float* s1 = ws;                                  // 8192
    float* s2 = s1 + 8192;                           // 8192
    __bf16* hFrag = (__bf16*)(s2 + 8192);            // 262144 float slots
    float* numP = (float*)(s2 + 8192 + 262144);      // 2048*1024
    float* denP = numP + 2048 * 1024;                // 2048*16

    k_fused<<<256, 256, 0, stream>>>(X, W, a, s1, s2, hFrag);
    k_attn_d<<<2048, 256, 0, stream>>>((const bf16x8*)hFrag, Adj, s1, s2, numP, denP);
    k_final<<<2048, 256, 0, stream>>>(numP, denP, out);
}